// Round 3
// baseline (1680.821 us; speedup 1.0000x reference)
//
#include <hip/hip_runtime.h>
#include <math.h>

#define NN 100000
#define EE 1600000
#define BB 64
#define FF 16
#define HH 128
#define GG 8
#define K0 19
#define BN_EPS 1e-5f
#define PCH 16
#define BSHIFT 8
#define NBINS 391      // ceil(NN / 256)
#define BCAP 8192      // mean 4092, +64 sigma

__device__ __forceinline__ float elu01f(float v) {
    return v > 0.f ? v : 0.1f * (__expf(v) - 1.f);
}

// ---------------- CSR build ----------------
// Phase A: degree count + radix binning of edges by dst>>BSHIFT
__global__ __launch_bounds__(256) void k_bin(const int* __restrict__ srcA, const int* __restrict__ dstA,
                                             int* __restrict__ cnt, int* __restrict__ bincnt,
                                             uint2* __restrict__ binbuf) {
    int e = blockIdx.x * 256 + threadIdx.x;
    if (e < EE) {
        int d = dstA[e];
        atomicAdd(&cnt[d], 1);
        int b = d >> BSHIFT;
        int pos = atomicAdd(&bincnt[b], 1);
        binbuf[(size_t)b * BCAP + pos] = make_uint2((unsigned)srcA[e], (unsigned)d);
    }
}

__global__ __launch_bounds__(256) void k_scan1(const int* __restrict__ cnt, int* __restrict__ excl,
                                               int* __restrict__ bsums) {
    __shared__ int sd[256];
    int tid = threadIdx.x;
    int base = blockIdx.x * 1024 + tid * 4;
    int v0 = 0, v1 = 0, v2 = 0, v3 = 0;
    if (base + 0 < NN) v0 = cnt[base + 0];
    if (base + 1 < NN) v1 = cnt[base + 1];
    if (base + 2 < NN) v2 = cnt[base + 2];
    if (base + 3 < NN) v3 = cnt[base + 3];
    sd[tid] = v0 + v1 + v2 + v3;
    __syncthreads();
    for (int off = 1; off < 256; off <<= 1) {
        int t = (tid >= off) ? sd[tid - off] : 0;
        __syncthreads();
        sd[tid] += t;
        __syncthreads();
    }
    if (tid == 255) bsums[blockIdx.x] = sd[255];
    int run = (tid > 0) ? sd[tid - 1] : 0;
    if (base + 0 < NN) { excl[base + 0] = run; run += v0; }
    if (base + 1 < NN) { excl[base + 1] = run; run += v1; }
    if (base + 2 < NN) { excl[base + 2] = run; run += v2; }
    if (base + 3 < NN) { excl[base + 3] = run; }
}

__global__ void k_scan2(int* bsums, int nb) {
    __shared__ int sd[128];
    int t = threadIdx.x;
    int v = (t < nb) ? bsums[t] : 0;
    sd[t] = v;
    __syncthreads();
    for (int off = 1; off < 128; off <<= 1) {
        int u = (t >= off) ? sd[t - off] : 0;
        __syncthreads();
        sd[t] += u;
        __syncthreads();
    }
    if (t < nb) bsums[t] = (t > 0) ? sd[t - 1] : 0;
}

__global__ __launch_bounds__(256) void k_scan3(const int* __restrict__ excl, const int* __restrict__ bsums,
                                               int* __restrict__ rp, int* __restrict__ cur) {
    int i = blockIdx.x * 256 + threadIdx.x;
    if (i < NN) {
        int v = excl[i] + bsums[i >> 10];
        rp[i] = v; cur[i] = v;
    }
    if (i == 0) rp[NN] = EE;
}

// Phase B: per-bin scatter — srcs positions for one bin span a contiguous
// L2-resident window; cur atomics hit only ~1KB of counters per block
__global__ __launch_bounds__(256) void k_scatter_bin(const uint2* __restrict__ binbuf,
                                                     const int* __restrict__ bincnt,
                                                     int* __restrict__ cur, int* __restrict__ srcs) {
    int b = blockIdx.x;
    int n = bincnt[b];
    const uint2* base = binbuf + (size_t)b * BCAP;
    for (int i = threadIdx.x; i < n; i += 256) {
        uint2 ed = base[i];
        int pos = atomicAdd(&cur[ed.y], 1);
        srcs[pos] = (int)ed.x;
    }
}

// graph boundaries via binary search on sorted batch
__global__ void k_gptr(const int* __restrict__ batch, int* __restrict__ gptr) {
    int t = threadIdx.x;
    if (t > BB) return;
    int lo = 0, hi = NN;
    while (lo < hi) { int mid = (lo + hi) >> 1; if (batch[mid] < t) lo = mid + 1; else hi = mid; }
    gptr[t] = lo;
}

// ---------------- feature build + aggregation ----------------
__global__ __launch_bounds__(256) void k_buildx0(const float* __restrict__ h0, const float* __restrict__ coord,
                                                 float* __restrict__ x0) {
    int i = blockIdx.x * 256 + threadIdx.x;
    if (i >= NN * K0) return;
    int node = i / K0, k = i - node * K0;
    x0[i] = (k < FF) ? h0[node * FF + k] : coord[node * 3 + (k - FF)];
}

__global__ __launch_bounds__(256) void k_agg_small(const float* __restrict__ x, const int* __restrict__ rp,
                                                   const int* __restrict__ srcs, float* __restrict__ y) {
    int w = (blockIdx.x * 256 + threadIdx.x) >> 6;
    int lane = threadIdx.x & 63;
    if (w >= NN) return;
    int beg = rp[w], end = rp[w + 1];
    bool act = lane < K0;
    size_t li = act ? (size_t)lane : 0;
    float acc0 = 0.f, acc1 = 0.f;
    if (act) acc0 = x[(size_t)w * K0 + li];
    int p = beg;
    for (; p + 8 <= end; p += 8) {
        int s0 = srcs[p + 0], s1 = srcs[p + 1], s2 = srcs[p + 2], s3 = srcs[p + 3];
        int s4 = srcs[p + 4], s5 = srcs[p + 5], s6 = srcs[p + 6], s7 = srcs[p + 7];
        float v0 = x[(size_t)s0 * K0 + li];
        float v1 = x[(size_t)s1 * K0 + li];
        float v2 = x[(size_t)s2 * K0 + li];
        float v3 = x[(size_t)s3 * K0 + li];
        float v4 = x[(size_t)s4 * K0 + li];
        float v5 = x[(size_t)s5 * K0 + li];
        float v6 = x[(size_t)s6 * K0 + li];
        float v7 = x[(size_t)s7 * K0 + li];
        acc0 += (v0 + v1) + (v2 + v3);
        acc1 += (v4 + v5) + (v6 + v7);
    }
    for (; p < end; ++p) {
        int sn = srcs[p];
        acc0 += x[(size_t)sn * K0 + li];
    }
    if (act) y[(size_t)w * K0 + lane] = acc0 + acc1;
}

__global__ __launch_bounds__(256) void k_agg128(const float* __restrict__ x, const int* __restrict__ rp,
                                                const int* __restrict__ srcs, float* __restrict__ y) {
    int w = (blockIdx.x * 256 + threadIdx.x) >> 6;
    int lane = threadIdx.x & 63;
    if (w >= NN) return;
    const float2* x2 = (const float2*)x;
    float2* y2 = (float2*)y;
    int beg = rp[w], end = rp[w + 1];
    float2 a0 = x2[(size_t)w * 64 + lane];
    float2 a1 = {0.f, 0.f};
    int p = beg;
    for (; p + 8 <= end; p += 8) {
        int s0 = srcs[p + 0], s1 = srcs[p + 1], s2 = srcs[p + 2], s3 = srcs[p + 3];
        int s4 = srcs[p + 4], s5 = srcs[p + 5], s6 = srcs[p + 6], s7 = srcs[p + 7];
        float2 v0 = x2[(size_t)s0 * 64 + lane];
        float2 v1 = x2[(size_t)s1 * 64 + lane];
        float2 v2 = x2[(size_t)s2 * 64 + lane];
        float2 v3 = x2[(size_t)s3 * 64 + lane];
        float2 v4 = x2[(size_t)s4 * 64 + lane];
        float2 v5 = x2[(size_t)s5 * 64 + lane];
        float2 v6 = x2[(size_t)s6 * 64 + lane];
        float2 v7 = x2[(size_t)s7 * 64 + lane];
        a0.x += (v0.x + v1.x) + (v2.x + v3.x);
        a0.y += (v0.y + v1.y) + (v2.y + v3.y);
        a1.x += (v4.x + v5.x) + (v6.x + v7.x);
        a1.y += (v4.y + v5.y) + (v6.y + v7.y);
    }
    for (; p < end; ++p) {
        int sn = srcs[p];
        float2 v = x2[(size_t)sn * 64 + lane];
        a0.x += v.x; a0.y += v.y;
    }
    a0.x += a1.x; a0.y += a1.y;
    y2[(size_t)w * 64 + lane] = a0;
}

// ---------------- GEMM: 32 rows x 128 cols per block ----------------
template<int K, bool STATS, bool BNIN, bool ELUOUT>
__global__ __launch_bounds__(256) void k_gemm(const float* __restrict__ in, const float* __restrict__ W,
        const float* __restrict__ bias, const float* __restrict__ bnscale, const float* __restrict__ bnshift,
        float* __restrict__ out, float* __restrict__ ssum, float* __restrict__ ssq) {
    constexpr int SK = ((K + 3) / 4) * 4 + 4;
    __shared__ __align__(16) float yt[32 * SK];
    __shared__ float red[256];
    int tid = threadIdx.x;
    int row0 = blockIdx.x * 32;
    for (int t = tid; t < 32 * SK; t += 256) {
        int r = t / SK, k = t - r * SK;
        float v = 0.f;
        if (k < K) {
            v = in[(size_t)(row0 + r) * K + k];
            if (BNIN) v = fmaxf(fmaf(v, bnscale[k], bnshift[k]), 0.f);
        }
        yt[t] = v;
    }
    __syncthreads();
    int col = tid & 127;
    int rg = tid >> 7;
    float acc[16];
    #pragma unroll
    for (int r = 0; r < 16; r++) acc[r] = 0.f;
    const float* ybase = &yt[rg * 16 * SK];
    int kk = 0;
    for (; kk + 4 <= K; kk += 4) {
        float w0 = W[(kk + 0) * HH + col];
        float w1 = W[(kk + 1) * HH + col];
        float w2 = W[(kk + 2) * HH + col];
        float w3 = W[(kk + 3) * HH + col];
        #pragma unroll
        for (int r = 0; r < 16; r++) {
            const float4 v = *(const float4*)&ybase[r * SK + kk];
            acc[r] = fmaf(v.x, w0, acc[r]);
            acc[r] = fmaf(v.y, w1, acc[r]);
            acc[r] = fmaf(v.z, w2, acc[r]);
            acc[r] = fmaf(v.w, w3, acc[r]);
        }
    }
    if constexpr (K % 4 != 0) {
        float w[4];
        #pragma unroll
        for (int j = 0; j < 4; j++) w[j] = (kk + j < K) ? W[(kk + j) * HH + col] : 0.f;
        #pragma unroll
        for (int r = 0; r < 16; r++) {
            const float4 v = *(const float4*)&ybase[r * SK + kk];
            acc[r] = fmaf(v.x, w[0], acc[r]);
            acc[r] = fmaf(v.y, w[1], acc[r]);
            acc[r] = fmaf(v.z, w[2], acc[r]);
            acc[r] = fmaf(v.w, w[3], acc[r]);
        }
    }
    float bcol = bias[col];
    float s = 0.f, s2 = 0.f;
    #pragma unroll
    for (int r = 0; r < 16; r++) {
        float hv = acc[r] + bcol;
        if (ELUOUT) hv = elu01f(hv);
        out[(size_t)(row0 + rg * 16 + r) * HH + col] = hv;
        if (STATS) { s += hv; s2 = fmaf(hv, hv, s2); }
    }
    if (STATS) {
        red[tid] = s; __syncthreads();
        if (tid < 128) atomicAdd(&ssum[col], s + red[tid + 128]);
        __syncthreads();
        red[tid] = s2; __syncthreads();
        if (tid < 128) atomicAdd(&ssq[col], s2 + red[tid + 128]);
    }
}

__global__ void k_bnfin(const float* ssum, const float* ssq, const float* __restrict__ gm,
                        const float* __restrict__ bt, float* scale, float* shift) {
    int c = threadIdx.x;
    float mu = ssum[c] * (1.f / NN);
    float var = fmaxf(ssq[c] * (1.f / NN) - mu * mu, 0.f);
    float a = gm[c] * rsqrtf(var + BN_EPS);
    scale[c] = a;
    shift[c] = fmaf(-mu, a, bt[c]);
}

// ---------------- pooling ----------------
__global__ __launch_bounds__(128) void k_pool_part(const float* __restrict__ x, const int* __restrict__ gptr,
                                                   float* __restrict__ psum, float* __restrict__ pmax) {
    int g = blockIdx.x >> 4;
    int ch = blockIdx.x & 15;
    int s = gptr[g], e = gptr[g + 1];
    int len = e - s;
    int per = (len + PCH - 1) / PCH;
    int lo = s + ch * per;
    int hi = min(lo + per, e);
    int c = threadIdx.x;
    float sm = 0.f, mx = -INFINITY;
    for (int i = lo; i < hi; ++i) {
        float v = x[(size_t)i * HH + c];
        sm += v; mx = fmaxf(mx, v);
    }
    psum[(size_t)blockIdx.x * HH + c] = sm;
    pmax[(size_t)blockIdx.x * HH + c] = mx;
}

__global__ __launch_bounds__(128) void k_pool_fin(const float* __restrict__ psum, const float* __restrict__ pmax,
                                                  const int* __restrict__ gptr, const float* __restrict__ g0,
                                                  float* __restrict__ z) {
    int g = blockIdx.x, c = threadIdx.x;
    float sm = 0.f, mx = -INFINITY;
    for (int ch = 0; ch < PCH; ++ch) {
        sm += psum[(size_t)(g * PCH + ch) * HH + c];
        mx = fmaxf(mx, pmax[(size_t)(g * PCH + ch) * HH + c]);
    }
    int cntn = gptr[g + 1] - gptr[g];
    float denom = (float)max(cntn, 1);
    z[g * 264 + c] = sm / denom;
    z[g * 264 + 128 + c] = mx;
    if (c < GG) z[g * 264 + 256 + c] = g0[g * GG + c];
}

// ---------------- classifier ----------------
__global__ __launch_bounds__(128) void k_cls1(const float* __restrict__ z, const float* __restrict__ cw1,
                                              const float* __restrict__ cb1, float* __restrict__ z1) {
    __shared__ float zr[264];
    int g = blockIdx.x, c = threadIdx.x;
    for (int t = c; t < 264; t += 128) zr[t] = z[g * 264 + t];
    __syncthreads();
    float acc = cb1[c];
    for (int k = 0; k < 264; ++k) acc = fmaf(zr[k], cw1[k * HH + c], acc);
    z1[g * HH + c] = elu01f(acc);
}

__global__ __launch_bounds__(128) void k_cls2(const float* __restrict__ z1, const float* __restrict__ cgm,
                                              const float* __restrict__ cbt, const float* __restrict__ cw2,
                                              const float* __restrict__ cb2, float* __restrict__ outp) {
    __shared__ float zn[HH * 65];
    int c = threadIdx.x;
    float s = 0.f, s2 = 0.f;
    for (int g = 0; g < BB; ++g) {
        float v = z1[g * HH + c];
        s += v; s2 = fmaf(v, v, s2);
    }
    float mu = s * (1.f / BB);
    float var = fmaxf(s2 * (1.f / BB) - mu * mu, 0.f);
    float a = cgm[c] * rsqrtf(var + BN_EPS);
    float sh = fmaf(-mu, a, cbt[c]);
    for (int g = 0; g < BB; ++g) zn[c * 65 + g] = fmaf(z1[g * HH + c], a, sh);
    __syncthreads();
    if (c < BB) {
        float l0 = cb2[0], l1 = cb2[1];
        for (int k = 0; k < HH; ++k) {
            float v = zn[k * 65 + c];
            l0 = fmaf(v, cw2[k * 2 + 0], l0);
            l1 = fmaf(v, cw2[k * 2 + 1], l1);
        }
        float m = fmaxf(l0, l1);
        float e0 = __expf(l0 - m), e1 = __expf(l1 - m);
        float inv = 1.f / (e0 + e1);
        outp[c * 2 + 0] = e0 * inv;
        outp[c * 2 + 1] = e1 * inv;
    }
}

extern "C" void kernel_launch(void* const* d_in, const int* in_sizes, int n_in,
                              void* d_out, int out_size, void* d_ws, size_t ws_size,
                              hipStream_t stream) {
    (void)in_sizes; (void)n_in; (void)out_size; (void)ws_size;
    const float* h0     = (const float*)d_in[0];
    const float* coord0 = (const float*)d_in[1];
    const float* g0     = (const float*)d_in[2];
    const int*   eidx   = (const int*)d_in[3];
    const int*   batch  = (const int*)d_in[4];
    const float* w1_0   = (const float*)d_in[5];
    const float* b1_0   = (const float*)d_in[6];
    const float* gm_0   = (const float*)d_in[7];
    const float* bt_0   = (const float*)d_in[8];
    const float* w2_0   = (const float*)d_in[9];
    const float* b2_0   = (const float*)d_in[10];
    const float* w1_r   = (const float*)d_in[11];
    const float* b1_r   = (const float*)d_in[12];
    const float* gm_r   = (const float*)d_in[13];
    const float* bt_r   = (const float*)d_in[14];
    const float* w2_r   = (const float*)d_in[15];
    const float* b2_r   = (const float*)d_in[16];
    const float* cw1    = (const float*)d_in[17];
    const float* cb1    = (const float*)d_in[18];
    const float* cgm    = (const float*)d_in[19];
    const float* cbt    = (const float*)d_in[20];
    const float* cw2    = (const float*)d_in[21];
    const float* cb2    = (const float*)d_in[22];
    float* outp = (float*)d_out;

    const int* esrc = eidx;
    const int* edst = eidx + EE;

    char* p = (char*)d_ws;
    auto alloc = [&](size_t bytes) { void* r = (void*)p; p += (bytes + 255) & ~(size_t)255; return r; };
    float* xb      = (float*)alloc((size_t)NN * HH * 4);
    float* yb      = (float*)alloc((size_t)NN * HH * 4);
    float* hb      = (float*)alloc((size_t)NN * HH * 4);
    int*   cnt     = (int*)alloc((size_t)NN * 4);
    int*   excl    = (int*)alloc((size_t)NN * 4);
    int*   rp      = (int*)alloc((size_t)(NN + 1) * 4);
    int*   cur     = (int*)alloc((size_t)NN * 4);
    int*   srcs    = (int*)alloc((size_t)EE * 4);
    int*   bsums   = (int*)alloc(128 * 4);
    int*   gptr    = (int*)alloc((BB + 1) * 4);
    int*   bincnt  = (int*)alloc((size_t)NBINS * 4);
    float* bnstat  = (float*)alloc(2 * HH * 4);   // sum | sumsq
    float* bnscale = (float*)alloc(HH * 4);
    float* bnshift = (float*)alloc(HH * 4);
    float* psum    = (float*)alloc((size_t)BB * PCH * HH * 4);
    float* pmax    = (float*)alloc((size_t)BB * PCH * HH * 4);
    float* zb      = (float*)alloc((size_t)BB * 264 * 4);
    float* z1b     = (float*)alloc((size_t)BB * HH * 4);
    // bin buffer overlays yb (dead until k_agg_small): 391*8192*8B = 25.6MB < 51.2MB
    uint2* binbuf  = (uint2*)yb;

    const int NB_SCAN1 = (NN + 1023) / 1024;        // 98
    const int NB_E = (EE + 255) / 256;              // 6250
    const int NB_N = (NN + 255) / 256;              // 391
    const int NB_AGG = (NN * 64 + 255) / 256;       // 25000
    const int NB_GEMM = NN / 32;                    // 3125
    const int NB_X0 = (NN * K0 + 255) / 256;

    // CSR build (radix-binned)
    hipMemsetAsync(cnt, 0, (size_t)NN * 4, stream);
    hipMemsetAsync(bincnt, 0, (size_t)NBINS * 4, stream);
    k_bin<<<NB_E, 256, 0, stream>>>(esrc, edst, cnt, bincnt, binbuf);
    k_scan1<<<NB_SCAN1, 256, 0, stream>>>(cnt, excl, bsums);
    k_scan2<<<1, 128, 0, stream>>>(bsums, NB_SCAN1);
    k_scan3<<<NB_N, 256, 0, stream>>>(excl, bsums, rp, cur);
    k_scatter_bin<<<NBINS, 256, 0, stream>>>(binbuf, bincnt, cur, srcs);
    k_gptr<<<1, 128, 0, stream>>>(batch, gptr);

    // layer 0: x0 [N,19]
    k_buildx0<<<NB_X0, 256, 0, stream>>>(h0, coord0, xb);
    k_agg_small<<<NB_AGG, 256, 0, stream>>>(xb, rp, srcs, yb);
    hipMemsetAsync(bnstat, 0, 2 * HH * 4, stream);
    k_gemm<K0, true, false, false><<<NB_GEMM, 256, 0, stream>>>(yb, w1_0, b1_0, nullptr, nullptr,
                                                                hb, bnstat, bnstat + HH);
    k_bnfin<<<1, 128, 0, stream>>>(bnstat, bnstat + HH, gm_0, bt_0, bnscale, bnshift);
    k_gemm<HH, false, true, true><<<NB_GEMM, 256, 0, stream>>>(hb, w2_0, b2_0, bnscale, bnshift,
                                                               xb, nullptr, nullptr);

    // layers 1..2
    for (int i = 0; i < 2; ++i) {
        k_agg128<<<NB_AGG, 256, 0, stream>>>(xb, rp, srcs, yb);
        hipMemsetAsync(bnstat, 0, 2 * HH * 4, stream);
        k_gemm<HH, true, false, false><<<NB_GEMM, 256, 0, stream>>>(yb, w1_r + (size_t)i * HH * HH,
                b1_r + i * HH, nullptr, nullptr, hb, bnstat, bnstat + HH);
        k_bnfin<<<1, 128, 0, stream>>>(bnstat, bnstat + HH, gm_r + i * HH, bt_r + i * HH, bnscale, bnshift);
        k_gemm<HH, false, true, true><<<NB_GEMM, 256, 0, stream>>>(hb, w2_r + (size_t)i * HH * HH,
                b2_r + i * HH, bnscale, bnshift, xb, nullptr, nullptr);
    }

    // pooling + classifier
    k_pool_part<<<BB * PCH, 128, 0, stream>>>(xb, gptr, psum, pmax);
    k_pool_fin<<<BB, 128, 0, stream>>>(psum, pmax, gptr, g0, zb);
    k_cls1<<<BB, 128, 0, stream>>>(zb, cw1, cb1, z1b);
    k_cls2<<<1, 128, 0, stream>>>(z1b, cgm, cbt, cw2, cb2, outp);
}

// Round 4
// 1190.386 us; speedup vs baseline: 1.4120x; 1.4120x over previous
//
#include <hip/hip_runtime.h>
#include <math.h>

#define NN 100000
#define EE 1600000
#define BB 64
#define FF 16
#define HH 128
#define GG 8
#define K0 19
#define BN_EPS 1e-5f
#define PCH 16

__device__ __forceinline__ float elu01f(float v) {
    return v > 0.f ? v : 0.1f * (__expf(v) - 1.f);
}

// ---------------- CSR build ----------------
__global__ __launch_bounds__(256) void k_count(const int* __restrict__ dst, int* __restrict__ cnt) {
    int e = blockIdx.x * 256 + threadIdx.x;
    if (e < EE) atomicAdd(&cnt[dst[e]], 1);
}

__global__ __launch_bounds__(256) void k_scan1(const int* __restrict__ cnt, int* __restrict__ excl,
                                               int* __restrict__ bsums) {
    __shared__ int sd[256];
    int tid = threadIdx.x;
    int base = blockIdx.x * 1024 + tid * 4;
    int v0 = 0, v1 = 0, v2 = 0, v3 = 0;
    if (base + 0 < NN) v0 = cnt[base + 0];
    if (base + 1 < NN) v1 = cnt[base + 1];
    if (base + 2 < NN) v2 = cnt[base + 2];
    if (base + 3 < NN) v3 = cnt[base + 3];
    sd[tid] = v0 + v1 + v2 + v3;
    __syncthreads();
    for (int off = 1; off < 256; off <<= 1) {
        int t = (tid >= off) ? sd[tid - off] : 0;
        __syncthreads();
        sd[tid] += t;
        __syncthreads();
    }
    if (tid == 255) bsums[blockIdx.x] = sd[255];
    int run = (tid > 0) ? sd[tid - 1] : 0;
    if (base + 0 < NN) { excl[base + 0] = run; run += v0; }
    if (base + 1 < NN) { excl[base + 1] = run; run += v1; }
    if (base + 2 < NN) { excl[base + 2] = run; run += v2; }
    if (base + 3 < NN) { excl[base + 3] = run; }
}

__global__ void k_scan2(int* bsums, int nb) {
    __shared__ int sd[128];
    int t = threadIdx.x;
    int v = (t < nb) ? bsums[t] : 0;
    sd[t] = v;
    __syncthreads();
    for (int off = 1; off < 128; off <<= 1) {
        int u = (t >= off) ? sd[t - off] : 0;
        __syncthreads();
        sd[t] += u;
        __syncthreads();
    }
    if (t < nb) bsums[t] = (t > 0) ? sd[t - 1] : 0;
}

__global__ __launch_bounds__(256) void k_scan3(const int* __restrict__ excl, const int* __restrict__ bsums,
                                               int* __restrict__ rp, int* __restrict__ cur) {
    int i = blockIdx.x * 256 + threadIdx.x;
    if (i < NN) {
        int v = excl[i] + bsums[i >> 10];
        rp[i] = v; cur[i] = v;
    }
    if (i == 0) rp[NN] = EE;
}

__global__ __launch_bounds__(256) void k_scatter(const int* __restrict__ srcA, const int* __restrict__ dstA,
                                                 int* __restrict__ cur, int* __restrict__ srcs) {
    int e = blockIdx.x * 256 + threadIdx.x;
    if (e < EE) {
        int d = dstA[e];
        int pos = atomicAdd(&cur[d], 1);
        srcs[pos] = srcA[e];
    }
}

// graph boundaries via binary search on sorted batch
__global__ void k_gptr(const int* __restrict__ batch, int* __restrict__ gptr) {
    int t = threadIdx.x;
    if (t > BB) return;
    int lo = 0, hi = NN;
    while (lo < hi) { int mid = (lo + hi) >> 1; if (batch[mid] < t) lo = mid + 1; else hi = mid; }
    gptr[t] = lo;
}

// ---------------- feature build + aggregation ----------------
__global__ __launch_bounds__(256) void k_buildx0(const float* __restrict__ h0, const float* __restrict__ coord,
                                                 float* __restrict__ x0) {
    int i = blockIdx.x * 256 + threadIdx.x;
    if (i >= NN * K0) return;
    int node = i / K0, k = i - node * K0;
    x0[i] = (k < FF) ? h0[node * FF + k] : coord[node * 3 + (k - FF)];
}

__global__ __launch_bounds__(256) void k_agg_small(const float* __restrict__ x, const int* __restrict__ rp,
                                                   const int* __restrict__ srcs, float* __restrict__ y) {
    int w = (blockIdx.x * 256 + threadIdx.x) >> 6;
    int lane = threadIdx.x & 63;
    if (w >= NN) return;
    int beg = rp[w], end = rp[w + 1];
    bool act = lane < K0;
    size_t li = act ? (size_t)lane : 0;
    float acc0 = 0.f, acc1 = 0.f;
    if (act) acc0 = x[(size_t)w * K0 + li];
    int p = beg;
    for (; p + 8 <= end; p += 8) {
        int s0 = srcs[p + 0], s1 = srcs[p + 1], s2 = srcs[p + 2], s3 = srcs[p + 3];
        int s4 = srcs[p + 4], s5 = srcs[p + 5], s6 = srcs[p + 6], s7 = srcs[p + 7];
        float v0 = x[(size_t)s0 * K0 + li];
        float v1 = x[(size_t)s1 * K0 + li];
        float v2 = x[(size_t)s2 * K0 + li];
        float v3 = x[(size_t)s3 * K0 + li];
        float v4 = x[(size_t)s4 * K0 + li];
        float v5 = x[(size_t)s5 * K0 + li];
        float v6 = x[(size_t)s6 * K0 + li];
        float v7 = x[(size_t)s7 * K0 + li];
        acc0 += (v0 + v1) + (v2 + v3);
        acc1 += (v4 + v5) + (v6 + v7);
    }
    for (; p < end; ++p) {
        int sn = srcs[p];
        acc0 += x[(size_t)sn * K0 + li];
    }
    if (act) y[(size_t)w * K0 + lane] = acc0 + acc1;
}

__global__ __launch_bounds__(256) void k_agg128(const float* __restrict__ x, const int* __restrict__ rp,
                                                const int* __restrict__ srcs, float* __restrict__ y) {
    int w = (blockIdx.x * 256 + threadIdx.x) >> 6;
    int lane = threadIdx.x & 63;
    if (w >= NN) return;
    const float2* x2 = (const float2*)x;
    float2* y2 = (float2*)y;
    int beg = rp[w], end = rp[w + 1];
    float2 a0 = x2[(size_t)w * 64 + lane];
    float2 a1 = {0.f, 0.f};
    int p = beg;
    for (; p + 8 <= end; p += 8) {
        int s0 = srcs[p + 0], s1 = srcs[p + 1], s2 = srcs[p + 2], s3 = srcs[p + 3];
        int s4 = srcs[p + 4], s5 = srcs[p + 5], s6 = srcs[p + 6], s7 = srcs[p + 7];
        float2 v0 = x2[(size_t)s0 * 64 + lane];
        float2 v1 = x2[(size_t)s1 * 64 + lane];
        float2 v2 = x2[(size_t)s2 * 64 + lane];
        float2 v3 = x2[(size_t)s3 * 64 + lane];
        float2 v4 = x2[(size_t)s4 * 64 + lane];
        float2 v5 = x2[(size_t)s5 * 64 + lane];
        float2 v6 = x2[(size_t)s6 * 64 + lane];
        float2 v7 = x2[(size_t)s7 * 64 + lane];
        a0.x += (v0.x + v1.x) + (v2.x + v3.x);
        a0.y += (v0.y + v1.y) + (v2.y + v3.y);
        a1.x += (v4.x + v5.x) + (v6.x + v7.x);
        a1.y += (v4.y + v5.y) + (v6.y + v7.y);
    }
    for (; p < end; ++p) {
        int sn = srcs[p];
        float2 v = x2[(size_t)sn * 64 + lane];
        a0.x += v.x; a0.y += v.y;
    }
    a0.x += a1.x; a0.y += a1.y;
    y2[(size_t)w * 64 + lane] = a0;
}

// ---------------- GEMM K=19 (layer-0 first MLP): 32 rows x 128 cols ----------------
template<int K, bool STATS>
__global__ __launch_bounds__(256) void k_gemm_small(const float* __restrict__ in, const float* __restrict__ W,
        const float* __restrict__ bias, float* __restrict__ out, float* __restrict__ ssum, float* __restrict__ ssq) {
    constexpr int SK = ((K + 3) / 4) * 4 + 4;
    __shared__ __align__(16) float yt[32 * SK];
    __shared__ float red[256];
    int tid = threadIdx.x;
    int row0 = blockIdx.x * 32;
    for (int t = tid; t < 32 * SK; t += 256) {
        int r = t / SK, k = t - r * SK;
        float v = 0.f;
        if (k < K) v = in[(size_t)(row0 + r) * K + k];
        yt[t] = v;
    }
    __syncthreads();
    int col = tid & 127;
    int rg = tid >> 7;
    float acc[16];
    #pragma unroll
    for (int r = 0; r < 16; r++) acc[r] = 0.f;
    const float* ybase = &yt[rg * 16 * SK];
    int kk = 0;
    for (; kk + 4 <= K; kk += 4) {
        float w0 = W[(kk + 0) * HH + col];
        float w1 = W[(kk + 1) * HH + col];
        float w2 = W[(kk + 2) * HH + col];
        float w3 = W[(kk + 3) * HH + col];
        #pragma unroll
        for (int r = 0; r < 16; r++) {
            const float4 v = *(const float4*)&ybase[r * SK + kk];
            acc[r] = fmaf(v.x, w0, acc[r]);
            acc[r] = fmaf(v.y, w1, acc[r]);
            acc[r] = fmaf(v.z, w2, acc[r]);
            acc[r] = fmaf(v.w, w3, acc[r]);
        }
    }
    if constexpr (K % 4 != 0) {
        float w[4];
        #pragma unroll
        for (int j = 0; j < 4; j++) w[j] = (kk + j < K) ? W[(kk + j) * HH + col] : 0.f;
        #pragma unroll
        for (int r = 0; r < 16; r++) {
            const float4 v = *(const float4*)&ybase[r * SK + kk];
            acc[r] = fmaf(v.x, w[0], acc[r]);
            acc[r] = fmaf(v.y, w[1], acc[r]);
            acc[r] = fmaf(v.z, w[2], acc[r]);
            acc[r] = fmaf(v.w, w[3], acc[r]);
        }
    }
    float bcol = bias[col];
    float s = 0.f, s2 = 0.f;
    #pragma unroll
    for (int r = 0; r < 16; r++) {
        float hv = acc[r] + bcol;
        out[(size_t)(row0 + rg * 16 + r) * HH + col] = hv;
        if (STATS) { s += hv; s2 = fmaf(hv, hv, s2); }
    }
    if (STATS) {
        red[tid] = s; __syncthreads();
        if (tid < 128) atomicAdd(&ssum[col], s + red[tid + 128]);
        __syncthreads();
        red[tid] = s2; __syncthreads();
        if (tid < 128) atomicAdd(&ssq[col], s2 + red[tid + 128]);
    }
}

// ---------------- GEMM K=128: 32 rows x 128 cols, 4x4 micro-tile/thread ----------------
template<bool STATS, bool BNIN, bool ELUOUT>
__global__ __launch_bounds__(256) void k_gemm128(const float* __restrict__ in, const float* __restrict__ W,
        const float* __restrict__ bias, const float* __restrict__ bnscale, const float* __restrict__ bnshift,
        float* __restrict__ out, float* __restrict__ ssum, float* __restrict__ ssq) {
    __shared__ __align__(16) float At[32 * 132];
    __shared__ float lsum[HH], lsq[HH];
    int tid = threadIdx.x;
    size_t row0 = (size_t)blockIdx.x * 32;
    if (STATS && tid < HH) { lsum[tid] = 0.f; lsq[tid] = 0.f; }
    // stage A tile (with optional BN+ReLU transform)
    {
        int r = tid >> 3;
        int kb = (tid & 7) * 16;
        const float4* s4 = (const float4*)(in + (row0 + r) * HH + kb);
        #pragma unroll
        for (int j = 0; j < 4; j++) {
            float4 v = s4[j];
            if (BNIN) {
                const float4 sc = *(const float4*)(bnscale + kb + j * 4);
                const float4 sh = *(const float4*)(bnshift + kb + j * 4);
                v.x = fmaxf(fmaf(v.x, sc.x, sh.x), 0.f);
                v.y = fmaxf(fmaf(v.y, sc.y, sh.y), 0.f);
                v.z = fmaxf(fmaf(v.z, sc.z, sh.z), 0.f);
                v.w = fmaxf(fmaf(v.w, sc.w, sh.w), 0.f);
            }
            *(float4*)(&At[r * 132 + kb + j * 4]) = v;
        }
    }
    __syncthreads();
    int colg = tid & 31, rowg = tid >> 5;
    int col0 = colg * 4;
    int r0 = rowg * 4;
    float acc[4][4];
    #pragma unroll
    for (int r = 0; r < 4; r++)
        #pragma unroll
        for (int c = 0; c < 4; c++) acc[r][c] = 0.f;
    const float* Abase = &At[r0 * 132];
    for (int k = 0; k < HH; k += 4) {
        float a_[4][4];
        #pragma unroll
        for (int r = 0; r < 4; r++) {
            float4 av = *(const float4*)(Abase + r * 132 + k);
            a_[r][0] = av.x; a_[r][1] = av.y; a_[r][2] = av.z; a_[r][3] = av.w;
        }
        #pragma unroll
        for (int j = 0; j < 4; j++) {
            float4 w = *(const float4*)(W + (size_t)(k + j) * HH + col0);
            #pragma unroll
            for (int r = 0; r < 4; r++) {
                acc[r][0] = fmaf(a_[r][j], w.x, acc[r][0]);
                acc[r][1] = fmaf(a_[r][j], w.y, acc[r][1]);
                acc[r][2] = fmaf(a_[r][j], w.z, acc[r][2]);
                acc[r][3] = fmaf(a_[r][j], w.w, acc[r][3]);
            }
        }
    }
    float4 bv = *(const float4*)(bias + col0);
    float s[4] = {0.f, 0.f, 0.f, 0.f}, s2[4] = {0.f, 0.f, 0.f, 0.f};
    #pragma unroll
    for (int r = 0; r < 4; r++) {
        float4 o;
        float hv0 = acc[r][0] + bv.x;
        float hv1 = acc[r][1] + bv.y;
        float hv2 = acc[r][2] + bv.z;
        float hv3 = acc[r][3] + bv.w;
        if (ELUOUT) { hv0 = elu01f(hv0); hv1 = elu01f(hv1); hv2 = elu01f(hv2); hv3 = elu01f(hv3); }
        o.x = hv0; o.y = hv1; o.z = hv2; o.w = hv3;
        *(float4*)(out + (row0 + r0 + r) * HH + col0) = o;
        if (STATS) {
            s[0] += hv0; s2[0] = fmaf(hv0, hv0, s2[0]);
            s[1] += hv1; s2[1] = fmaf(hv1, hv1, s2[1]);
            s[2] += hv2; s2[2] = fmaf(hv2, hv2, s2[2]);
            s[3] += hv3; s2[3] = fmaf(hv3, hv3, s2[3]);
        }
    }
    if (STATS) {
        #pragma unroll
        for (int c = 0; c < 4; c++) {
            atomicAdd(&lsum[col0 + c], s[c]);
            atomicAdd(&lsq[col0 + c], s2[c]);
        }
        __syncthreads();
        if (tid < HH) {
            atomicAdd(&ssum[tid], lsum[tid]);
            atomicAdd(&ssq[tid], lsq[tid]);
        }
    }
}

__global__ void k_bnfin(const float* ssum, const float* ssq, const float* __restrict__ gm,
                        const float* __restrict__ bt, float* scale, float* shift) {
    int c = threadIdx.x;
    float mu = ssum[c] * (1.f / NN);
    float var = fmaxf(ssq[c] * (1.f / NN) - mu * mu, 0.f);
    float a = gm[c] * rsqrtf(var + BN_EPS);
    scale[c] = a;
    shift[c] = fmaf(-mu, a, bt[c]);
}

// ---------------- pooling ----------------
__global__ __launch_bounds__(128) void k_pool_part(const float* __restrict__ x, const int* __restrict__ gptr,
                                                   float* __restrict__ psum, float* __restrict__ pmax) {
    int g = blockIdx.x >> 4;
    int ch = blockIdx.x & 15;
    int s = gptr[g], e = gptr[g + 1];
    int len = e - s;
    int per = (len + PCH - 1) / PCH;
    int lo = s + ch * per;
    int hi = min(lo + per, e);
    int c = threadIdx.x;
    float sm = 0.f, mx = -INFINITY;
    for (int i = lo; i < hi; ++i) {
        float v = x[(size_t)i * HH + c];
        sm += v; mx = fmaxf(mx, v);
    }
    psum[(size_t)blockIdx.x * HH + c] = sm;
    pmax[(size_t)blockIdx.x * HH + c] = mx;
}

__global__ __launch_bounds__(128) void k_pool_fin(const float* __restrict__ psum, const float* __restrict__ pmax,
                                                  const int* __restrict__ gptr, const float* __restrict__ g0,
                                                  float* __restrict__ z) {
    int g = blockIdx.x, c = threadIdx.x;
    float sm = 0.f, mx = -INFINITY;
    for (int ch = 0; ch < PCH; ++ch) {
        sm += psum[(size_t)(g * PCH + ch) * HH + c];
        mx = fmaxf(mx, pmax[(size_t)(g * PCH + ch) * HH + c]);
    }
    int cntn = gptr[g + 1] - gptr[g];
    float denom = (float)max(cntn, 1);
    z[g * 264 + c] = sm / denom;
    z[g * 264 + 128 + c] = mx;
    if (c < GG) z[g * 264 + 256 + c] = g0[g * GG + c];
}

// ---------------- classifier ----------------
__global__ __launch_bounds__(128) void k_cls1(const float* __restrict__ z, const float* __restrict__ cw1,
                                              const float* __restrict__ cb1, float* __restrict__ z1) {
    __shared__ float zr[264];
    int g = blockIdx.x, c = threadIdx.x;
    for (int t = c; t < 264; t += 128) zr[t] = z[g * 264 + t];
    __syncthreads();
    float acc = cb1[c];
    for (int k = 0; k < 264; ++k) acc = fmaf(zr[k], cw1[k * HH + c], acc);
    z1[g * HH + c] = elu01f(acc);
}

__global__ __launch_bounds__(128) void k_cls2(const float* __restrict__ z1, const float* __restrict__ cgm,
                                              const float* __restrict__ cbt, const float* __restrict__ cw2,
                                              const float* __restrict__ cb2, float* __restrict__ outp) {
    __shared__ float zn[HH * 65];
    int c = threadIdx.x;
    float s = 0.f, s2 = 0.f;
    for (int g = 0; g < BB; ++g) {
        float v = z1[g * HH + c];
        s += v; s2 = fmaf(v, v, s2);
    }
    float mu = s * (1.f / BB);
    float var = fmaxf(s2 * (1.f / BB) - mu * mu, 0.f);
    float a = cgm[c] * rsqrtf(var + BN_EPS);
    float sh = fmaf(-mu, a, cbt[c]);
    for (int g = 0; g < BB; ++g) zn[c * 65 + g] = fmaf(z1[g * HH + c], a, sh);
    __syncthreads();
    if (c < BB) {
        float l0 = cb2[0], l1 = cb2[1];
        for (int k = 0; k < HH; ++k) {
            float v = zn[k * 65 + c];
            l0 = fmaf(v, cw2[k * 2 + 0], l0);
            l1 = fmaf(v, cw2[k * 2 + 1], l1);
        }
        float m = fmaxf(l0, l1);
        float e0 = __expf(l0 - m), e1 = __expf(l1 - m);
        float inv = 1.f / (e0 + e1);
        outp[c * 2 + 0] = e0 * inv;
        outp[c * 2 + 1] = e1 * inv;
    }
}

extern "C" void kernel_launch(void* const* d_in, const int* in_sizes, int n_in,
                              void* d_out, int out_size, void* d_ws, size_t ws_size,
                              hipStream_t stream) {
    (void)in_sizes; (void)n_in; (void)out_size; (void)ws_size;
    const float* h0     = (const float*)d_in[0];
    const float* coord0 = (const float*)d_in[1];
    const float* g0     = (const float*)d_in[2];
    const int*   eidx   = (const int*)d_in[3];
    const int*   batch  = (const int*)d_in[4];
    const float* w1_0   = (const float*)d_in[5];
    const float* b1_0   = (const float*)d_in[6];
    const float* gm_0   = (const float*)d_in[7];
    const float* bt_0   = (const float*)d_in[8];
    const float* w2_0   = (const float*)d_in[9];
    const float* b2_0   = (const float*)d_in[10];
    const float* w1_r   = (const float*)d_in[11];
    const float* b1_r   = (const float*)d_in[12];
    const float* gm_r   = (const float*)d_in[13];
    const float* bt_r   = (const float*)d_in[14];
    const float* w2_r   = (const float*)d_in[15];
    const float* b2_r   = (const float*)d_in[16];
    const float* cw1    = (const float*)d_in[17];
    const float* cb1    = (const float*)d_in[18];
    const float* cgm    = (const float*)d_in[19];
    const float* cbt    = (const float*)d_in[20];
    const float* cw2    = (const float*)d_in[21];
    const float* cb2    = (const float*)d_in[22];
    float* outp = (float*)d_out;

    const int* esrc = eidx;
    const int* edst = eidx + EE;

    char* p = (char*)d_ws;
    auto alloc = [&](size_t bytes) { void* r = (void*)p; p += (bytes + 255) & ~(size_t)255; return r; };
    float* xb      = (float*)alloc((size_t)NN * HH * 4);
    float* yb      = (float*)alloc((size_t)NN * HH * 4);
    float* hb      = (float*)alloc((size_t)NN * HH * 4);
    int*   cnt     = (int*)alloc((size_t)NN * 4);
    int*   excl    = (int*)alloc((size_t)NN * 4);
    int*   rp      = (int*)alloc((size_t)(NN + 1) * 4);
    int*   cur     = (int*)alloc((size_t)NN * 4);
    int*   srcs    = (int*)alloc((size_t)EE * 4);
    int*   bsums   = (int*)alloc(128 * 4);
    int*   gptr    = (int*)alloc((BB + 1) * 4);
    float* bnstat  = (float*)alloc(2 * HH * 4);   // sum | sumsq
    float* bnscale = (float*)alloc(HH * 4);
    float* bnshift = (float*)alloc(HH * 4);
    float* psum    = (float*)alloc((size_t)BB * PCH * HH * 4);
    float* pmax    = (float*)alloc((size_t)BB * PCH * HH * 4);
    float* zb      = (float*)alloc((size_t)BB * 264 * 4);
    float* z1b     = (float*)alloc((size_t)BB * HH * 4);

    const int NB_SCAN1 = (NN + 1023) / 1024;        // 98
    const int NB_E = (EE + 255) / 256;              // 6250
    const int NB_N = (NN + 255) / 256;              // 391
    const int NB_AGG = (NN * 64 + 255) / 256;       // 25000
    const int NB_GEMM = NN / 32;                    // 3125
    const int NB_X0 = (NN * K0 + 255) / 256;

    // CSR build
    hipMemsetAsync(cnt, 0, (size_t)NN * 4, stream);
    k_count<<<NB_E, 256, 0, stream>>>(edst, cnt);
    k_scan1<<<NB_SCAN1, 256, 0, stream>>>(cnt, excl, bsums);
    k_scan2<<<1, 128, 0, stream>>>(bsums, NB_SCAN1);
    k_scan3<<<NB_N, 256, 0, stream>>>(excl, bsums, rp, cur);
    k_scatter<<<NB_E, 256, 0, stream>>>(esrc, edst, cur, srcs);
    k_gptr<<<1, 128, 0, stream>>>(batch, gptr);

    // layer 0: x0 [N,19]
    k_buildx0<<<NB_X0, 256, 0, stream>>>(h0, coord0, xb);
    k_agg_small<<<NB_AGG, 256, 0, stream>>>(xb, rp, srcs, yb);
    hipMemsetAsync(bnstat, 0, 2 * HH * 4, stream);
    k_gemm_small<K0, true><<<NB_GEMM, 256, 0, stream>>>(yb, w1_0, b1_0, hb, bnstat, bnstat + HH);
    k_bnfin<<<1, 128, 0, stream>>>(bnstat, bnstat + HH, gm_0, bt_0, bnscale, bnshift);
    k_gemm128<false, true, true><<<NB_GEMM, 256, 0, stream>>>(hb, w2_0, b2_0, bnscale, bnshift,
                                                              xb, nullptr, nullptr);

    // layers 1..2
    for (int i = 0; i < 2; ++i) {
        k_agg128<<<NB_AGG, 256, 0, stream>>>(xb, rp, srcs, yb);
        hipMemsetAsync(bnstat, 0, 2 * HH * 4, stream);
        k_gemm128<true, false, false><<<NB_GEMM, 256, 0, stream>>>(yb, w1_r + (size_t)i * HH * HH,
                b1_r + i * HH, nullptr, nullptr, hb, bnstat, bnstat + HH);
        k_bnfin<<<1, 128, 0, stream>>>(bnstat, bnstat + HH, gm_r + i * HH, bt_r + i * HH, bnscale, bnshift);
        k_gemm128<false, true, true><<<NB_GEMM, 256, 0, stream>>>(hb, w2_r + (size_t)i * HH * HH,
                b2_r + i * HH, bnscale, bnshift, xb, nullptr, nullptr);
    }

    // pooling + classifier
    k_pool_part<<<BB * PCH, 128, 0, stream>>>(xb, gptr, psum, pmax);
    k_pool_fin<<<BB, 128, 0, stream>>>(psum, pmax, gptr, g0, zb);
    k_cls1<<<BB, 128, 0, stream>>>(zb, cw1, cb1, z1b);
    k_cls2<<<1, 128, 0, stream>>>(z1b, cgm, cbt, cw2, cb2, outp);
}